// Round 1
// 464.006 us; speedup vs baseline: 1.0425x; 1.0425x over previous
//
#include <hip/hip_runtime.h>
#include <math.h>

#define Bn 4
#define C_ORIc 90
#define C_MNTc 180
#define C_OFFc 8
#define IMG    262144              // 512*512

// output offsets (floats), concatenated in return order:
// minut [B,K,4], keep [B,K], enh_vis [B,H,W], mask_up*255 [B,H,W], ori_field [B,H,W]
#define O_MINUT 0
#define O_KEEP  (Bn*1024*4)
#define O_VIS   (O_KEEP + Bn*1024)
#define O_MASK  (O_VIS + Bn*IMG)
#define O_ORI   (O_MASK + Bn*IMG)

#define PI_180 0.017453292519943295f
#define TWO_PI 6.283185307179586f
#define ANG_T  0.5235987755982988f

// ---------------------------------------------------------------------------
// Binary morphology helpers: rows are 160-bit (5 words) with virtual pad words.
// Erosion pad = all-ones (AND-neutral), dilation pad = zeros (OR-neutral).
// h_and/h_or compute w &= (w >> k) combined across word boundaries.
// ---------------------------------------------------------------------------
__device__ __forceinline__ void h_and(unsigned* w, int k) {
    unsigned t[7];
    #pragma unroll
    for (int i = 0; i < 7; i++) {
        unsigned hi = (i < 6) ? w[i + 1] : 0xFFFFFFFFu;
        t[i] = w[i] & ((w[i] >> k) | (hi << (32 - k)));
    }
    #pragma unroll
    for (int i = 0; i < 7; i++) w[i] = t[i];
}

__device__ __forceinline__ void h_or(unsigned* w, int k) {
    unsigned t[7];
    #pragma unroll
    for (int i = 0; i < 7; i++) {
        unsigned hi = (i < 6) ? w[i + 1] : 0u;
        t[i] = w[i] | ((w[i] >> k) | (hi << (32 - k)));
    }
    #pragma unroll
    for (int i = 0; i < 7; i++) w[i] = t[i];
}

// bits j of a word (covering cols base..base+31) where lo <= base+j <= hi
__device__ __forceinline__ unsigned rangemask(int lo, int hi, int base) {
    int a = lo - base, b2 = hi - base;
    if (a < 0) a = 0;
    if (b2 > 31) b2 = 31;
    if (a > b2) return 0u;
    unsigned m = (b2 == 31) ? 0xFFFFFFFFu : ((1u << (b2 + 1)) - 1u);
    return m & (0xFFFFFFFFu << a);
}

// ---------------------------------------------------------------------------
// KA: fused pipeline.
//  blocks 0..255  : per-image 64x64 output tile; full 40x40 binary opening of
//                   round(segup) computed in LDS from a 142x142-bit halo tile
//                   (erosion: AND windows, dilation: OR windows, log-doubling).
//                   Writes mask*255, ori_field, mask bit-plane (ws), and the
//                   per-tile min/max of enh*mask (ws, no atomics).
//  blocks 256..259: minutiae detect for image b (identical to prior version).
// NOTE: binary (bit) morphology is exact because round(uniform[0,1)) ∈ {0,1}.
// ---------------------------------------------------------------------------
__global__ __launch_bounds__(256) void ka_main(
    const float* __restrict__ segup, const float* __restrict__ seg,
    const float* __restrict__ mscore, const float* __restrict__ mo,
    const float* __restrict__ xo, const float* __restrict__ yo,
    const float* __restrict__ ori, const float* __restrict__ enh,
    float* __restrict__ out, float* __restrict__ ws)
{
    __shared__ union {
        unsigned long long keys[4096];   // detect: 32 KB sort keys
        float scr[8320];                 // detect: opening ping-pong / NMS arrays
        struct {
            unsigned bb[4][852];         // tile: 4 bit-buffers, 142 rows x 6 words
            unsigned maskw[128];         // tile: final 64x64 mask bits
            float red[256];              // tile: min/max reduction
        } t;
    } U;
    __shared__ unsigned smBits[128];     // detect: packed 64x64 small mask
    __shared__ unsigned short smHalf[256];

    int tid = threadIdx.x;

    if (blockIdx.x >= 256) {
        // ---------------- detect block for image b (unchanged) -------------
        int b = blockIdx.x - 256;

        const float* sg = seg + b * 4096;
        float* scr0 = U.scr;
        float* scr1 = U.scr + 4160;
        for (int i = tid; i < 4096; i += 256)
            scr0[(i >> 6) * 65 + (i & 63)] = rintf(sg[i]);
        __syncthreads();
        for (int i = tid; i < 4096; i += 256) {        // vertical min
            int r = i >> 6, c = i & 63;
            int lo = max(r - 2, 0), hi = min(r + 2, 63);
            float m = 1e30f;
            for (int rr = lo; rr <= hi; rr++) m = fminf(m, scr0[rr * 65 + c]);
            scr1[r * 65 + c] = m;
        }
        __syncthreads();
        for (int i = tid; i < 4096; i += 256) {        // horizontal min
            int r = i >> 6, c = i & 63;
            int lo = max(c - 2, 0), hi = min(c + 2, 63);
            float m = 1e30f;
            for (int cc = lo; cc <= hi; cc++) m = fminf(m, scr1[r * 65 + cc]);
            scr0[r * 65 + c] = m;
        }
        __syncthreads();
        for (int i = tid; i < 4096; i += 256) {        // vertical max
            int r = i >> 6, c = i & 63;
            int lo = max(r - 2, 0), hi = min(r + 2, 63);
            float m = -1e30f;
            for (int rr = lo; rr <= hi; rr++) m = fmaxf(m, scr0[rr * 65 + c]);
            scr1[r * 65 + c] = m;
        }
        __syncthreads();
        {   // horizontal max -> packed bits (16 cells/thread, same row)
            unsigned short bits16 = 0;
            int i0 = tid * 16;
            int r = i0 >> 6;
            for (int j = 0; j < 16; j++) {
                int c = (i0 + j) & 63;
                int lo = max(c - 2, 0), hi = min(c + 2, 63);
                float m = -1e30f;
                for (int cc = lo; cc <= hi; cc++) m = fmaxf(m, scr1[r * 65 + cc]);
                bits16 |= ((unsigned short)(m != 0.0f)) << j;
            }
            smHalf[tid] = bits16;
        }
        __syncthreads();
        if (tid < 128)
            smBits[tid] = (unsigned)smHalf[2 * tid] | ((unsigned)smHalf[2 * tid + 1] << 16);
        __syncthreads();

        // fast path: no masked score above THRESH -> all detect outputs zero
        const float* sp = mscore + b * 4096;
        bool anyv = false;
        for (int i = tid; i < 4096; i += 256) {
            unsigned m = (smBits[i >> 5] >> (i & 31)) & 1u;
            anyv |= (m && sp[i] > 0.5f);
        }
        if (!__syncthreads_or(anyv)) {
            float4 z = {0.f, 0.f, 0.f, 0.f};
            float4* mo4 = (float4*)(out + O_MINUT + (size_t)b * 4096);
            for (int i = tid; i < 1024; i += 256) mo4[i] = z;
            ((float4*)(out + O_KEEP + (size_t)b * 1024))[tid] = z;
            return;
        }

        // slow path: full bitonic sort (exact jax.lax.top_k semantics) + NMS
        for (int i = tid; i < 4096; i += 256) {
            unsigned m = (smBits[i >> 5] >> (i & 31)) & 1u;
            float s = m ? sp[i] : 0.0f;
            float mval = (s > 0.5f) ? s : -1.0f;
            unsigned fb = __float_as_uint(mval);
            unsigned od = (fb & 0x80000000u) ? ~fb : (fb | 0x80000000u);
            U.keys[i] = ((unsigned long long)(~od) << 32) | (unsigned)i;
        }
        for (int k = 2; k <= 4096; k <<= 1) {
            for (int j = k >> 1; j > 0; j >>= 1) {
                __syncthreads();
                for (int t = tid; t < 4096; t += 256) {
                    int ixj = t ^ j;
                    if (ixj > t) {
                        unsigned long long va = U.keys[t], vb = U.keys[ixj];
                        bool up = ((t & k) == 0);
                        if ((va > vb) == up) { U.keys[t] = vb; U.keys[ixj] = va; }
                    }
                }
            }
        }
        __syncthreads();

        int idxs[4]; float ss[4]; int vld[4];
        int Nv = 0;
        for (int j = 0; j < 4; j++) {
            int slot = tid + j * 256;
            int idx = (int)(U.keys[slot] & 0xffffffffu);
            unsigned m = (smBits[idx >> 5] >> (idx & 31)) & 1u;
            float s = m ? sp[idx] : 0.0f;
            idxs[j] = idx; ss[j] = s; vld[j] = (s > 0.5f);
            Nv += __syncthreads_count(vld[j]);
        }

        float xcs[4], ycs[4], angs[4];
        for (int j = 0; j < 4; j++) {
            int slot = tid + j * 256;
            xcs[j] = ycs[j] = angs[j] = 0.f;
            if (slot < Nv) {
                int idx = idxs[j];
                int rr = idx >> 6, cc = idx & 63;
                const float* op_ = mo + (size_t)b * C_MNTc * 4096 + idx;
                float best = op_[0]; int bi = 0;
                for (int ch = 1; ch < C_MNTc; ch++) {
                    float v = op_[ch * 4096];
                    if (v > best) { best = v; bi = ch; }
                }
                const float* xp = xo + (size_t)b * C_OFFc * 4096 + idx;
                float bxv = xp[0]; int bx = 0;
                for (int ch = 1; ch < C_OFFc; ch++) {
                    float v = xp[ch * 4096];
                    if (v > bxv) { bxv = v; bx = ch; }
                }
                const float* yp = yo + (size_t)b * C_OFFc * 4096 + idx;
                float byv = yp[0]; int by = 0;
                for (int ch = 1; ch < C_OFFc; ch++) {
                    float v = yp[ch * 4096];
                    if (v > byv) { byv = v; by = ch; }
                }
                angs[j] = ((float)bi * 2.0f - 89.0f) * PI_180;
                xcs[j]  = (float)cc * 8.0f + (float)bx;
                ycs[j]  = (float)rr * 8.0f + (float)by;
            }
        }
        __syncthreads();   // keys dead; alias NMS arrays
        float* sx = U.scr;
        float* sy = U.scr + 1024;
        float* sa = U.scr + 2048;
        int*   keep = (int*)(U.scr + 3072);
        for (int j = 0; j < 4; j++) {
            int slot = tid + j * 256;
            sx[slot] = xcs[j]; sy[slot] = ycs[j]; sa[slot] = angs[j];
            keep[slot] = (slot < Nv) ? 1 : 0;
        }
        __syncthreads();

        for (int i = 0; i < Nv; i++) {
            if (keep[i]) {
                float xi = sx[i], yi = sy[i], ai = sa[i];
                for (int j = 0; j < 4; j++) {
                    int slot = tid + j * 256;
                    if (slot > i && slot < Nv && keep[slot]) {
                        float dx = xcs[j] - xi, dy = ycs[j] - yi;
                        float d = sqrtf(dx * dx + dy * dy);
                        float da = fabsf(angs[j] - ai);
                        da = fminf(da, TWO_PI - da);
                        if (d < 16.0f && da < ANG_T) keep[slot] = 0;
                    }
                }
            }
            __syncthreads();
        }
        for (int j = 0; j < 4; j++) {
            int slot = tid + j * 256;
            int kf = keep[slot];
            float* mout = out + O_MINUT + (size_t)b * 4096 + slot * 4;
            if (kf) {
                mout[0] = xcs[j]; mout[1] = ycs[j]; mout[2] = angs[j]; mout[3] = ss[j];
            } else {
                mout[0] = 0.f; mout[1] = 0.f; mout[2] = 0.f; mout[3] = 0.f;
            }
            out[O_KEEP + b * 1024 + slot] = (float)kf;
        }
        return;
    }

    // ------------------- tile opening path ---------------------------------
    int b  = blockIdx.x >> 6;
    int tt = blockIdx.x & 63;
    int R0 = (tt >> 3) * 64;
    int C0 = (tt & 7) * 64;

    // Stage A: pack 142x142 binarized halo tile into bb[0] via wave ballots.
    // local (r, lc) <-> global (R0-38+r, C0-38+lc). OOB / pad lanes = 1 (AND-neutral).
    {
        int wv = tid >> 6, lane = tid & 63;
        const float* sup = segup + (size_t)b * IMG;
        for (int r = wv; r < 142; r += 4) {
            int gR = R0 - 38 + r;
            bool rowin = ((unsigned)gR < 512u);
            #pragma unroll
            for (int sgi = 0; sgi < 3; sgi++) {
                int lc = sgi * 64 + lane;
                int gc = C0 - 38 + lc;
                bool pred = true;
                if (rowin && lc < 142 && gc >= 0 && gc < 512)
                    pred = (rintf(sup[gR * 512 + gc]) != 0.0f);
                unsigned long long bal = __ballot(pred);
                if (lane == 0) {
                    U.t.bb[0][r * 6 + sgi * 2]     = (unsigned)bal;
                    U.t.bb[0][r * 6 + sgi * 2 + 1] = (unsigned)(bal >> 32);
                }
            }
        }
    }
    __syncthreads();

    // window-40 combine over rows via log-doubling: W40[r] = A32[r] & A8[r+32]
    #define VOP(DST, SRC, D, N, OPER)                                          \
        for (int idx = tid; idx < (N) * 5; idx += 256) {                       \
            int rr = idx / 5, wi = idx - rr * 5;                               \
            U.t.bb[DST][rr * 6 + wi] =                                         \
                U.t.bb[SRC][rr * 6 + wi] OPER U.t.bb[SRC][(rr + (D)) * 6 + wi];\
        }                                                                      \
        __syncthreads();

    // Stage B: vertical erosion (AND over 40 rows), output rows 0..102 in bb[0]
    VOP(1, 0, 1, 141, &)    // A2
    VOP(2, 1, 2, 139, &)    // A4
    VOP(3, 2, 4, 135, &)    // A8 (kept in bb[3])
    VOP(1, 3, 8, 127, &)    // A16
    VOP(2, 1, 16, 111, &)   // A32
    for (int idx = tid; idx < 103 * 5; idx += 256) {
        int rr = idx / 5, wi = idx - rr * 5;
        U.t.bb[0][rr * 6 + wi] = U.t.bb[2][rr * 6 + wi] & U.t.bb[3][(rr + 32) * 6 + wi];
    }
    __syncthreads();

    // Stage C: horizontal erosion (AND over 40 cols) + validity masking -> bb[1].
    // T2 local (r,c) <-> global (R0-19+r, C0-19+c); zero outside image / c>102.
    if (tid < 103) {
        unsigned w[7], s8[7];
        #pragma unroll
        for (int i = 0; i < 5; i++) w[i] = U.t.bb[0][tid * 6 + i];
        w[5] = w[6] = 0xFFFFFFFFu;
        h_and(w, 1); h_and(w, 2); h_and(w, 4);
        #pragma unroll
        for (int i = 0; i < 7; i++) s8[i] = w[i];
        h_and(w, 8); h_and(w, 16);
        unsigned res[5];
        #pragma unroll
        for (int i = 0; i < 5; i++) res[i] = w[i] & s8[i + 1];  // & shr(B8,32)
        bool rowok = ((unsigned)(R0 - 19 + tid) < 512u);
        int lo = 19 - C0;  if (lo < 0) lo = 0;
        int hi = 531 - C0; if (hi > 102) hi = 102;
        #pragma unroll
        for (int i = 0; i < 5; i++) {
            unsigned cm = rangemask(lo, hi, i * 32);
            U.t.bb[1][tid * 6 + i] = rowok ? (res[i] & cm) : 0u;
        }
    }
    __syncthreads();

    // Stage D: vertical dilation (OR over 40 rows), output rows 0..63 in bb[1]
    VOP(2, 1, 1, 102, |)    // O2
    VOP(0, 2, 2, 100, |)    // O4
    VOP(3, 0, 4, 96, |)     // O8 (kept in bb[3])
    VOP(2, 3, 8, 88, |)     // O16
    VOP(0, 2, 16, 72, |)    // O32
    for (int idx = tid; idx < 64 * 5; idx += 256) {
        int rr = idx / 5, wi = idx - rr * 5;
        U.t.bb[1][rr * 6 + wi] = U.t.bb[0][rr * 6 + wi] | U.t.bb[3][(rr + 32) * 6 + wi];
    }
    __syncthreads();
    #undef VOP

    // Stage E: horizontal dilation (OR over 40 cols) -> final 64x64 mask bits.
    unsigned* wsbits = (unsigned*)(ws + 512);
    if (tid < 64) {
        unsigned w[7], s8[7];
        #pragma unroll
        for (int i = 0; i < 5; i++) w[i] = U.t.bb[1][tid * 6 + i];
        w[5] = w[6] = 0u;
        h_or(w, 1); h_or(w, 2); h_or(w, 4);
        #pragma unroll
        for (int i = 0; i < 7; i++) s8[i] = w[i];
        h_or(w, 8); h_or(w, 16);
        unsigned m0 = w[0] | s8[1];
        unsigned m1 = w[1] | s8[2];
        U.t.maskw[tid * 2]     = m0;
        U.t.maskw[tid * 2 + 1] = m1;
        size_t bro = ((size_t)b * 512 + R0 + tid) * 16 + (C0 >> 5);
        wsbits[bro]     = m0;
        wsbits[bro + 1] = m1;
    }
    __syncthreads();

    // Stage F: outputs. thread -> row r = tid>>2, 16 cols at (tid&3)*16.
    {
        int r  = tid >> 2;
        int cg = (tid & 3) * 16;
        unsigned w0 = U.t.maskw[r * 2], w1 = U.t.maskw[r * 2 + 1];
        size_t base = (size_t)b * IMG + (size_t)(R0 + r) * 512 + C0 + cg;
        float lmin = 1e30f, lmax = -1e30f;
        for (int q = 0; q < 4; q++) {
            int c = cg + q * 4;
            float4 e = *((const float4*)(enh + base + q * 4));
            float mf[4], ov[4];
            #pragma unroll
            for (int j = 0; j < 4; j++) {
                int cc = c + j;
                unsigned bit = (((cc < 32) ? w0 : w1) >> (cc & 31)) & 1u;
                mf[j] = bit ? 1.0f : 0.0f;
                ov[j] = 0.0f;
                if (bit) {
                    const float* op_ = ori + (size_t)b * C_ORIc * IMG
                                     + (size_t)(R0 + r) * 512 + (C0 + cc);
                    float best = op_[0]; int bi = 0;
                    for (int ch = 1; ch < C_ORIc; ch++) {
                        float v = op_[(size_t)ch * IMG];
                        if (v > best) { best = v; bi = ch; }
                    }
                    ov[j] = ((float)bi * 2.0f - 90.0f) * PI_180 * mf[j];
                }
            }
            float4 mk = {mf[0] * 255.f, mf[1] * 255.f, mf[2] * 255.f, mf[3] * 255.f};
            *((float4*)(out + O_MASK + base + q * 4)) = mk;
            float4 o4 = {ov[0], ov[1], ov[2], ov[3]};
            *((float4*)(out + O_ORI + base + q * 4)) = o4;
            float e0 = e.x * mf[0], e1 = e.y * mf[1], e2 = e.z * mf[2], e3 = e.w * mf[3];
            lmin = fminf(lmin, fminf(fminf(e0, e1), fminf(e2, e3)));
            lmax = fmaxf(lmax, fmaxf(fmaxf(e0, e1), fmaxf(e2, e3)));
        }
        U.t.red[tid] = lmin;
        __syncthreads();
        for (int s = 128; s > 0; s >>= 1) {
            if (tid < s) U.t.red[tid] = fminf(U.t.red[tid], U.t.red[tid + s]);
            __syncthreads();
        }
        float bmn = U.t.red[0];
        __syncthreads();
        U.t.red[tid] = lmax;
        __syncthreads();
        for (int s = 128; s > 0; s >>= 1) {
            if (tid < s) U.t.red[tid] = fmaxf(U.t.red[tid], U.t.red[tid + s]);
            __syncthreads();
        }
        if (tid == 0) {
            ws[b * 64 + tt]       = bmn;          // per-tile min of enh*mask
            ws[256 + b * 64 + tt] = U.t.red[0];   // per-tile max
        }
    }
}

// ---------------------------------------------------------------------------
// KB: normalize enhanced image. Per-image min/max from the 64 per-tile values
// (one wave-shuffle reduction, redundant across waves), mask from bit-plane.
// ---------------------------------------------------------------------------
__global__ __launch_bounds__(256) void kb_vis(const float* __restrict__ enh,
                                              const float* __restrict__ ws,
                                              float* __restrict__ out)
{
    int i4 = blockIdx.x * 256 + threadIdx.x;   // Bn*H*W/4 float4s, 65536/img
    int b = i4 >> 16;
    int lane = threadIdx.x & 63;
    float vmin = ws[b * 64 + lane];
    float vmax = ws[256 + b * 64 + lane];
    #pragma unroll
    for (int off = 32; off > 0; off >>= 1) {
        vmin = fminf(vmin, __shfl_xor(vmin, off));
        vmax = fmaxf(vmax, __shfl_xor(vmax, off));
    }
    float den = vmax - vmin + 1e-8f;
    const unsigned* bits = (const unsigned*)(ws + 512);
    int p = (i4 & 65535) * 4;
    int row = p >> 9, col = p & 511;
    unsigned wv = bits[((size_t)b * 512 + row) * 16 + (col >> 5)];
    unsigned sh = col & 31;
    float4 e = ((const float4*)enh)[i4];
    float4 o;
    o.x = (e.x * (((wv >> (sh + 0)) & 1u) ? 1.f : 0.f) - vmin) / den * 255.0f;
    o.y = (e.y * (((wv >> (sh + 1)) & 1u) ? 1.f : 0.f) - vmin) / den * 255.0f;
    o.z = (e.z * (((wv >> (sh + 2)) & 1u) ? 1.f : 0.f) - vmin) / den * 255.0f;
    o.w = (e.w * (((wv >> (sh + 3)) & 1u) ? 1.f : 0.f) - vmin) / den * 255.0f;
    ((float4*)(out + O_VIS))[i4] = o;
}

extern "C" void kernel_launch(void* const* d_in, const int* in_sizes, int n_in,
                              void* d_out_, int out_size, void* d_ws, size_t ws_size,
                              hipStream_t stream)
{
    const float* seg    = (const float*)d_in[0];
    const float* segup  = (const float*)d_in[1];
    const float* oriup  = (const float*)d_in[2];
    const float* enh    = (const float*)d_in[3];
    const float* mscore = (const float*)d_in[4];
    const float* mori   = (const float*)d_in[5];
    const float* mxo    = (const float*)d_in[6];
    const float* myo    = (const float*)d_in[7];
    float* out = (float*)d_out_;

    // ws layout: [0..255] per-tile min, [256..511] per-tile max,
    //            [512..] mask bit-plane (Bn * 512 rows * 16 words = 128 KB)
    float* ws = (float*)d_ws;

    ka_main<<<260, 256, 0, stream>>>(segup, seg, mscore, mori, mxo, myo,
                                     oriup, enh, out, ws);
    kb_vis<<<1024, 256, 0, stream>>>(enh, ws, out);
}